// Round 8
// baseline (399.329 us; speedup 1.0000x reference)
//
#include <hip/hip_runtime.h>
#include <hip/hip_bf16.h>
#include <stdint.h>

#define N_NODES 10000
#define N_EDGES 160000
#define BUCKET 128
#define UNROLL_SLOTS 24   // slots [0,24) processed branchlessly; pre-zeroed by k_convert_init

typedef unsigned short u16;
typedef unsigned int u32;
typedef short s16v8 __attribute__((ext_vector_type(8)));
typedef float f32v4 __attribute__((ext_vector_type(4)));
typedef float f32v2 __attribute__((ext_vector_type(2)));
typedef unsigned int u32v4 __attribute__((ext_vector_type(4)));
typedef unsigned int u32v2 __attribute__((ext_vector_type(2)));

__device__ __forceinline__ float bf2f(u16 v){ return __uint_as_float(((u32)v) << 16); }
__device__ __forceinline__ u16 f2bf(float f){
    u32 u = __float_as_uint(f);
    u32 r = (u + 0x7fffu + ((u >> 16) & 1u)) >> 16;
    return (u16)r;
}
// unpack u32 holding 2 bf16 -> float2 (lo, hi)
__device__ __forceinline__ f32v2 up2(u32 v){
    f32v2 r;
    r.x = __uint_as_float(v << 16);
    r.y = __uint_as_float(v & 0xffff0000u);
    return r;
}
__device__ __forceinline__ u32 pk2(float lo, float hi){
    return (u32)f2bf(lo) | ((u32)f2bf(hi) << 16);
}

// ---------------- weights fp32->bf16 (+tconv transpose) + graph init + epack pad-zero ----------------
struct SmallPtrs { const void* p[14]; };

__device__ __constant__ const int g_seg_off[15] = {
    0, 12288, 12416, 16512, 16576, 41152, 41280,
    65856, 65984, 70080, 70144, 94720, 94848, 104064, 104076
};
// 0=straight, 1=tconv CIN=32 transpose, 2=tconv CIN=64 transpose
__device__ __constant__ const int g_seg_kind[14] = {
    1, 0, 0, 0, 2, 0, 2, 0, 0, 0, 2, 0, 0, 0
};

// grid covers max(104076, N_NODES*UNROLL_SLOTS=240000) threads
__global__ void k_convert_init(SmallPtrs ps, u16* __restrict__ dst,
                               float* deg, int* cur, int2* __restrict__ ep){
    int i = blockIdx.x * blockDim.x + threadIdx.x;
    if (i < 104076){
        int seg = 0, base = 0;
#pragma unroll
        for (int s = 0; s < 14; s++){
            if (i >= g_seg_off[s]){ seg = s; base = g_seg_off[s]; }
        }
        int li = i - base;
        float v = ((const float*)ps.p[seg])[li];
        int kind = g_seg_kind[seg];
        int dsto = li;
        if (kind){
            int CIN = (kind == 1) ? 32 : 64;
            int o = li / (3 * CIN);
            int rem = li - o * (3 * CIN);
            int c = rem / 3, d = rem - c * 3;
            dsto = d * 128 * CIN + o * CIN + c;     // [d][o][c]
        }
        dst[base + dsto] = f2bf(v);
    }
    if (i < N_NODES){ deg[i] = 1.0f; cur[i] = 0; }
    if (i < N_NODES * UNROLL_SLOTS){
        // pre-zero pad slots; scatter overwrites [0,cnt) afterwards, pads [cnt,24) stay {0,0}
        int n = i / UNROLL_SLOTS, s = i - n * UNROLL_SLOTS;
        ep[(size_t)n * BUCKET + s] = make_int2(0, 0);
    }
}

// ---------------- merged: gconv32 (blocks 0..1249) || deg + bucket-scatter (1250..1874) ----------------
// LDS union: xT [8][14][40] (8960 B) overlaid with Ho [8][12][72] (13824 B) -> 13.8 KB total.
__launch_bounds__(256, 4)
__global__ void k_gconv_count(const float* __restrict__ xin, const u16* __restrict__ wg,
                              const u16* __restrict__ bg, u16* __restrict__ out,
                              const int* __restrict__ ei, const float* __restrict__ ew,
                              float* deg, int* cur, int2* __restrict__ epack){
    if (blockIdx.x >= 1250){
        int e = (blockIdx.x - 1250) * 256 + threadIdx.x;
        if (e < N_EDGES){
            int s = ei[e];
            int d = ei[N_EDGES + e];
            float wv = ew[e];
            atomicAdd(&deg[d], wv);
            int p = atomicAdd(&cur[d], 1);
            if (p < BUCKET) epack[d * BUCKET + p] = make_int2(s, __float_as_int(wv));
        }
        return;
    }
    __shared__ __attribute__((aligned(16))) u16 shbuf[6912];   // 13824 B union
    u16* xT = shbuf;    // [g][row][c] = g*560 + row*40 + c  (rows 0..13, c 0..39)
    u16* Ho = shbuf;    // [g][t][o]   = g*864 + t*72 + o    (after MFMA, overwrites xT)
    int tid = threadIdx.x;
    int n0 = blockIdx.x * 8;

    int lane = tid & 63, wave = tid >> 6;
    int col = lane & 15, quad = lane >> 4;
    int o_p = wave * 16 + col, o_q = o_p + 64;

    s16v8 Bf[3][2];
#pragma unroll
    for (int pq = 0; pq < 2; pq++){
        int o = pq ? o_q : o_p;
#pragma unroll
        for (int d = 0; d < 3; d++)
            Bf[d][pq] = *(const s16v8*)(wg + d * 4096 + o * 32 + quad * 8);
    }

    for (int i = tid; i < 8 * 40; i += 256){
        int g = i / 40, c = i % 40;
        xT[g * 560 + 0 * 40 + c] = 0; xT[g * 560 + 13 * 40 + c] = 0;
    }
    {
        int g = tid >> 5, c = tid & 31;
        const float4* p = (const float4*)(xin + ((size_t)(n0 + g) * 32 + c) * 12);
        float4 v0 = p[0], v1 = p[1], v2 = p[2];
        u16* xb = xT + g * 560 + c;
        xb[1 * 40] = f2bf(v0.x);  xb[2 * 40] = f2bf(v0.y);
        xb[3 * 40] = f2bf(v0.z);  xb[4 * 40] = f2bf(v0.w);
        xb[5 * 40] = f2bf(v1.x);  xb[6 * 40] = f2bf(v1.y);
        xb[7 * 40] = f2bf(v1.z);  xb[8 * 40] = f2bf(v1.w);
        xb[9 * 40] = f2bf(v2.x);  xb[10 * 40] = f2bf(v2.y);
        xb[11 * 40] = f2bf(v2.z); xb[12 * 40] = f2bf(v2.w);
    }
    __syncthreads();

    f32v4 aP[6], aQ[6];
#pragma unroll
    for (int mt = 0; mt < 6; mt++){ aP[mt] = (f32v4)0.f; aQ[mt] = (f32v4)0.f; }
#pragma unroll
    for (int mt = 0; mt < 6; mt++){
        int m = mt * 16 + col;
        int g = m / 12, t = m - 12 * g;
#pragma unroll
        for (int d = 0; d < 3; d++){
            s16v8 a = *(const s16v8*)&xT[g * 560 + (t + d) * 40 + quad * 8];
            aP[mt] = __builtin_amdgcn_mfma_f32_16x16x32_bf16(a, Bf[d][0], aP[mt], 0, 0, 0);
            aQ[mt] = __builtin_amdgcn_mfma_f32_16x16x32_bf16(a, Bf[d][1], aQ[mt], 0, 0, 0);
        }
    }
    __syncthreads();   // all xT reads done before Ho overwrites the union buffer
    float bP = bf2f(bg[o_p]), bQ = bf2f(bg[o_q]);
#pragma unroll
    for (int mt = 0; mt < 6; mt++){
#pragma unroll
        for (int r = 0; r < 4; r++){
            int m2 = mt * 16 + quad * 4 + r;
            int g = m2 / 12, t = m2 - 12 * g;
            float pv = aP[mt][r] + bP, qv = aQ[mt][r] + bQ;
            Ho[g * 864 + t * 72 + o_p] = f2bf(pv / (1.f + __expf(-qv)));
        }
    }
    __syncthreads();
    for (int i = tid; i < 768; i += 256){
        int g = i / 96, r = i % 96, t = r / 8, ch = r % 8;
        *(s16v8*)(out + (size_t)(n0 + g) * 768 + t * 64 + ch * 8) =
            *(const s16v8*)&Ho[g * 864 + t * 72 + ch * 8];
    }
}

// ---------------- merged gather + fused MFMA pipeline ----------------
// Per block: 8 nodes. Gather phase: 32 lanes/node, lane owns feats {l*8..+7, 256+l*8..+7,
// 512+l*8..+7} (3 x 512B lane-contiguous loads per edge row). Branchless zero-padded
// slots [0,24). NORM=true (pass 1): normalize raw edge weights on the fly
// (w = raw * rsqrt(deg[src]) * rsqrt(deg[dst]) -- same op order as the old k_norm, lane 0
// writes back) so the k_norm dispatch is eliminated; pass 2 reads stored normalized w.
// Gather is fabric-random-traffic-bound (~1.7-1.8 TB/s ceiling, occupancy-insensitive per
// R4 A/B) -> added deg loads/rsqrt hide under it. launch_bounds(256,4): proven config;
// (256,5) caused a 48-VGPR spill configuration (+77 MB scratch traffic, R6).
#define XIDX(g, row, c) (((g) * 14 + (row)) * 72 + (c))

#define GFMA(W, A0, A1, A2) { \
    acc[0]  += (W) * up2((A0).x); acc[1]  += (W) * up2((A0).y); \
    acc[2]  += (W) * up2((A0).z); acc[3]  += (W) * up2((A0).w); \
    acc[4]  += (W) * up2((A1).x); acc[5]  += (W) * up2((A1).y); \
    acc[6]  += (W) * up2((A1).z); acc[7]  += (W) * up2((A1).w); \
    acc[8]  += (W) * up2((A2).x); acc[9]  += (W) * up2((A2).y); \
    acc[10] += (W) * up2((A2).z); acc[11] += (W) * up2((A2).w); }

#define GPAIR(P) { \
    int4 m = *(const int4*)(eb + (P)); \
    const u16* q0 = src + (size_t)(u32)m.x * 768 + fo; \
    const u16* q1 = src + (size_t)(u32)m.z * 768 + fo; \
    u32v4 a0 = *(const u32v4*)(q0); \
    u32v4 a1 = *(const u32v4*)(q0 + 256); \
    u32v4 a2 = *(const u32v4*)(q0 + 512); \
    u32v4 c0 = *(const u32v4*)(q1); \
    u32v4 c1 = *(const u32v4*)(q1 + 256); \
    u32v4 c2 = *(const u32v4*)(q1 + 512); \
    float w0f, w1f; \
    if (NORM){ \
        w0f = __int_as_float(m.y) * rsqrtf(deg[(u32)m.x]) * rdn; \
        w1f = __int_as_float(m.w) * rsqrtf(deg[(u32)m.z]) * rdn; \
        if (l == 0){ \
            int4 mw; mw.x = m.x; mw.y = __float_as_int(w0f); \
            mw.z = m.z; mw.w = __float_as_int(w1f); \
            *(int4*)(ebw + (P)) = mw; \
        } \
    } else { \
        w0f = __int_as_float(m.y); w1f = __int_as_float(m.w); \
    } \
    f32v2 w0; w0.x = w0f; w0.y = w0f; \
    f32v2 w1; w1.x = w1f; w1.y = w1f; \
    GFMA(w0, a0, a1, a2); \
    GFMA(w1, c0, c1, c2); }

#define GSINGLE(P) { \
    int2 e0 = eb[(P)]; \
    const u16* q0 = src + (size_t)(u32)e0.x * 768 + fo; \
    u32v4 a0 = *(const u32v4*)(q0); \
    u32v4 a1 = *(const u32v4*)(q0 + 256); \
    u32v4 a2 = *(const u32v4*)(q0 + 512); \
    float w0f; \
    if (NORM){ \
        w0f = __int_as_float(e0.y) * rsqrtf(deg[(u32)e0.x]) * rdn; \
        if (l == 0){ \
            int2 ww; ww.x = e0.x; ww.y = __float_as_int(w0f); \
            ebw[(P)] = ww; \
        } \
    } else { \
        w0f = __int_as_float(e0.y); \
    } \
    f32v2 w0; w0.x = w0f; w0.y = w0f; \
    GFMA(w0, a0, a1, a2); }

template<bool LAST, bool NORM>
__launch_bounds__(256, 4)
__global__ void k_gfused(const u16* __restrict__ src,   // bufA or bufB: [n][768] bf16 rows
                         const float* __restrict__ deg, const int* __restrict__ cur,
                         int2* __restrict__ ep,
                         const u16* __restrict__ Wmix, const u16* __restrict__ bmix,
                         const u16* __restrict__ w1, const u16* __restrict__ b1,
                         const u16* __restrict__ w2, const u16* __restrict__ b2,
                         const u16* __restrict__ fw, const u16* __restrict__ fb,
                         u16* __restrict__ outMid, float* __restrict__ outFin){
    __shared__ __attribute__((aligned(16))) u16 bufX[8 * 14 * 72];
    __shared__ __attribute__((aligned(16))) u16 bufY[8 * 14 * 72];
    int tid = threadIdx.x;
    int n0 = blockIdx.x * 8;
    int lane = tid & 63, wave = tid >> 6;
    int col = lane & 15, quad = lane >> 4;
    int o_p = wave * 16 + col, o_q = o_p + 64;

    // zero time-pad rows
    for (int i = tid; i < 8 * 72; i += 256){
        int g = i / 72, c = i % 72;
        bufX[XIDX(g, 0, c)] = 0; bufX[XIDX(g, 13, c)] = 0;
        bufY[XIDX(g, 0, c)] = 0; bufY[XIDX(g, 13, c)] = 0;
    }

    // ---- gather phase: 32 lanes per node ----
    {
        int nl = tid >> 5;               // node within block 0..7
        int l  = tid & 31;               // feature lane
        int n  = n0 + nl;
        int fo = l * 8;                  // u16 offset of this lane's first 8-feat group
        int e = cur[n]; if (e > BUCKET) e = BUCKET;   // early; used only in rare tail
        float rdn = 0.f;
        if (NORM) rdn = rsqrtf(deg[n]);  // broadcast load

        f32v2 acc[12];
        {
            float sw = 1.0f / deg[n];    // self-loop: dis[n]*1*dis[n]
            f32v2 swv; swv.x = sw; swv.y = sw;
            const u16* q = src + (size_t)n * 768 + fo;
            u32v4 s0 = *(const u32v4*)(q);
            u32v4 s1 = *(const u32v4*)(q + 256);
            u32v4 s2 = *(const u32v4*)(q + 512);
            acc[0]  = swv * up2(s0.x); acc[1]  = swv * up2(s0.y);
            acc[2]  = swv * up2(s0.z); acc[3]  = swv * up2(s0.w);
            acc[4]  = swv * up2(s1.x); acc[5]  = swv * up2(s1.y);
            acc[6]  = swv * up2(s1.z); acc[7]  = swv * up2(s1.w);
            acc[8]  = swv * up2(s2.x); acc[9]  = swv * up2(s2.y);
            acc[10] = swv * up2(s2.z); acc[11] = swv * up2(s2.w);
        }

        const int2* eb = ep + (size_t)n * BUCKET;
        int2* ebw = ep + (size_t)n * BUCKET;
        // branchless: slots [0,24) zero-padded (pads: w=0 -> exact 0 contribution)
        GPAIR(0);  GPAIR(2);  GPAIR(4);  GPAIR(6);
        GPAIR(8);  GPAIR(10); GPAIR(12); GPAIR(14);
        GPAIR(16); GPAIR(18); GPAIR(20); GPAIR(22);

        // rare tail (P(deg>24) ~ 2%)
        if (e > UNROLL_SLOTS){
            int p = UNROLL_SLOTS;
            for (; p + 1 < e; p += 2) GPAIR(p);
            if (p < e) GSINGLE(p);
        }

        // write results straight into bufX rows 1..12 (feats gi*256 + l*8 .. +7)
#pragma unroll
        for (int gi = 0; gi < 3; gi++){
            int f0 = gi * 256 + fo;
            int t = f0 >> 6, c = f0 & 63;
            u32v4 hv;
            hv.x = pk2(acc[4 * gi + 0].x, acc[4 * gi + 0].y);
            hv.y = pk2(acc[4 * gi + 1].x, acc[4 * gi + 1].y);
            hv.z = pk2(acc[4 * gi + 2].x, acc[4 * gi + 2].y);
            hv.w = pk2(acc[4 * gi + 3].x, acc[4 * gi + 3].y);
            *(u32v4*)&bufX[XIDX(nl, 1 + t, c)] = hv;
        }
    }
    __syncthreads();

    // ---- mix MFMA: y = relu(z*W + b), 6 m-tiles ----
    {
        f32v4 accm[6];
#pragma unroll
        for (int mt = 0; mt < 6; mt++) accm[mt] = (f32v4)0.f;
#pragma unroll
        for (int ks = 0; ks < 2; ks++){
            s16v8 Bm = *(const s16v8*)(Wmix + (size_t)o_p * 64 + ks * 32 + quad * 8);
#pragma unroll
            for (int mt = 0; mt < 6; mt++){
                int m = mt * 16 + col;
                int g = m / 12, t = m - 12 * g;
                s16v8 a = *(const s16v8*)&bufX[XIDX(g, 1 + t, ks * 32 + quad * 8)];
                accm[mt] = __builtin_amdgcn_mfma_f32_16x16x32_bf16(a, Bm, accm[mt], 0, 0, 0);
            }
        }
        float bm = bf2f(bmix[o_p]);
#pragma unroll
        for (int mt = 0; mt < 6; mt++){
#pragma unroll
            for (int r = 0; r < 4; r++){
                int m2 = mt * 16 + quad * 4 + r;
                int g = m2 / 12, t = m2 - 12 * g;
                bufY[XIDX(g, 1 + t, o_p)] = f2bf(fmaxf(accm[mt][r] + bm, 0.f));
            }
        }
    }
    __syncthreads();

    // ---- gated conv 1: bufY -> bufX ----
    {
        f32v4 aP[6], aQ[6];
#pragma unroll
        for (int mt = 0; mt < 6; mt++){ aP[mt] = (f32v4)0.f; aQ[mt] = (f32v4)0.f; }
#pragma unroll
        for (int ks = 0; ks < 2; ks++){
            s16v8 Bf[3][2];
#pragma unroll
            for (int pq = 0; pq < 2; pq++){
                int o = pq ? o_q : o_p;
#pragma unroll
                for (int d = 0; d < 3; d++)
                    Bf[d][pq] = *(const s16v8*)(w1 + d * 8192 + o * 64 + ks * 32 + quad * 8);
            }
#pragma unroll
            for (int mt = 0; mt < 6; mt++){
                int m = mt * 16 + col;
                int g = m / 12, t = m - 12 * g;
#pragma unroll
                for (int d = 0; d < 3; d++){
                    s16v8 a = *(const s16v8*)&bufY[XIDX(g, t + d, ks * 32 + quad * 8)];
                    aP[mt] = __builtin_amdgcn_mfma_f32_16x16x32_bf16(a, Bf[d][0], aP[mt], 0, 0, 0);
                    aQ[mt] = __builtin_amdgcn_mfma_f32_16x16x32_bf16(a, Bf[d][1], aQ[mt], 0, 0, 0);
                }
            }
        }
        float bP = bf2f(b1[o_p]), bQ = bf2f(b1[o_q]);
#pragma unroll
        for (int mt = 0; mt < 6; mt++){
#pragma unroll
            for (int r = 0; r < 4; r++){
                int m2 = mt * 16 + quad * 4 + r;
                int g = m2 / 12, t = m2 - 12 * g;
                float pv = aP[mt][r] + bP, qv = aQ[mt][r] + bQ;
                u16 hv = f2bf(pv / (1.f + __expf(-qv)));
                if (LAST) bufX[g * 1008 + o_p * 12 + t] = hv;   // H2[g][c*12+t]
                else      bufX[XIDX(g, 1 + t, o_p)] = hv;
            }
        }
    }
    __syncthreads();

    if (!LAST){
        // ---- gated conv 2: bufX -> bufY -> outMid ----
        f32v4 aP[6], aQ[6];
#pragma unroll
        for (int mt = 0; mt < 6; mt++){ aP[mt] = (f32v4)0.f; aQ[mt] = (f32v4)0.f; }
#pragma unroll
        for (int ks = 0; ks < 2; ks++){
            s16v8 Bf[3][2];
#pragma unroll
            for (int pq = 0; pq < 2; pq++){
                int o = pq ? o_q : o_p;
#pragma unroll
                for (int d = 0; d < 3; d++)
                    Bf[d][pq] = *(const s16v8*)(w2 + d * 8192 + o * 64 + ks * 32 + quad * 8);
            }
#pragma unroll
            for (int mt = 0; mt < 6; mt++){
                int m = mt * 16 + col;
                int g = m / 12, t = m - 12 * g;
#pragma unroll
                for (int d = 0; d < 3; d++){
                    s16v8 a = *(const s16v8*)&bufX[XIDX(g, t + d, ks * 32 + quad * 8)];
                    aP[mt] = __builtin_amdgcn_mfma_f32_16x16x32_bf16(a, Bf[d][0], aP[mt], 0, 0, 0);
                    aQ[mt] = __builtin_amdgcn_mfma_f32_16x16x32_bf16(a, Bf[d][1], aQ[mt], 0, 0, 0);
                }
            }
        }
        float bP = bf2f(b2[o_p]), bQ = bf2f(b2[o_q]);
#pragma unroll
        for (int mt = 0; mt < 6; mt++){
#pragma unroll
            for (int r = 0; r < 4; r++){
                int m2 = mt * 16 + quad * 4 + r;
                int g = m2 / 12, t = m2 - 12 * g;
                float pv = aP[mt][r] + bP, qv = aQ[mt][r] + bQ;
                bufY[XIDX(g, 1 + t, o_p)] = f2bf(pv / (1.f + __expf(-qv)));
            }
        }
        __syncthreads();
        for (int i = tid; i < 768; i += 256){
            int g = i / 96, r = i % 96, t = r / 8, ch = r % 8;
            *(s16v8*)(outMid + (size_t)(n0 + g) * 768 + t * 64 + ch * 8) =
                *(const s16v8*)&bufY[XIDX(g, 1 + t, ch * 8)];
        }
    } else {
        // ---- final: out[g][o] = sum_k H2[g][k]*fw[o][k] + fb[o] (wave 0; 8 nodes in rows 0..7) ----
        if (wave == 0){
            f32v4 accF = {0.f, 0.f, 0.f, 0.f};
            int g8 = col & 7;
#pragma unroll
            for (int ks = 0; ks < 24; ks++){
                s16v8 a = *(const s16v8*)&bufX[g8 * 1008 + ks * 32 + quad * 8];
                s16v8 bfr = {0, 0, 0, 0, 0, 0, 0, 0};
                if (col < 12)
                    bfr = *(const s16v8*)(fw + (size_t)col * 768 + ks * 32 + quad * 8);
                accF = __builtin_amdgcn_mfma_f32_16x16x32_bf16(a, bfr, accF, 0, 0, 0);
            }
            if (col < 12 && quad < 2){
                float bb = bf2f(fb[col]);
#pragma unroll
                for (int r = 0; r < 4; r++){
                    int g = quad * 4 + r;
                    outFin[(size_t)(n0 + g) * 12 + col] = accF[r] + bb;
                }
            }
        }
    }
}

// ---------------- launch ----------------
static inline size_t align256(size_t x){ return (x + 255) & ~(size_t)255; }

extern "C" void kernel_launch(void* const* d_in, const int* in_sizes, int n_in,
                              void* d_out, int out_size, void* d_ws, size_t ws_size,
                              hipStream_t stream){
    const float* x  = (const float*)d_in[0];
    const int* ei   = (const int*)d_in[1];
    const float* ew = (const float*)d_in[2];

    char* w = (char*)d_ws;
    u16* bufA    = (u16*)w;  w += align256((size_t)N_NODES * 768 * sizeof(u16));
    u16* bufB    = (u16*)w;  w += align256((size_t)N_NODES * 768 * sizeof(u16));
    float* deg   = (float*)w; w += align256(N_NODES * sizeof(float));
    int* cur     = (int*)w;   w += align256(N_NODES * sizeof(int));
    int2* epack  = (int2*)w;  w += align256((size_t)N_NODES * BUCKET * sizeof(int2));
    u16* cvt     = (u16*)w;   w += align256(104076 * sizeof(u16));

    u16* tc1a_w = cvt + 0;        // [d][128][32]
    u16* tc1a_b = cvt + 12288;
    u16* gc1_w  = cvt + 12416;
    u16* gc1_b  = cvt + 16512;
    u16* tc1b_w = cvt + 16576;    // [d][128][64]
    u16* tc1b_b = cvt + 41152;
    u16* tc2a_w = cvt + 41280;    // [d][128][64]
    u16* tc2a_b = cvt + 65856;
    u16* gc2_w  = cvt + 65984;
    u16* gc2_b  = cvt + 70080;
    u16* tc2b_w = cvt + 70144;    // [d][128][64]
    u16* tc2b_b = cvt + 94720;
    u16* fin_w  = cvt + 94848;
    u16* fin_b  = cvt + 104064;

    SmallPtrs ps;
    ps.p[0]  = d_in[3];  ps.p[1]  = d_in[4];
    ps.p[2]  = d_in[5];  ps.p[3]  = d_in[6];
    ps.p[4]  = d_in[7];  ps.p[5]  = d_in[8];
    ps.p[6]  = d_in[9];  ps.p[7]  = d_in[10];
    ps.p[8]  = d_in[11]; ps.p[9]  = d_in[12];
    ps.p[10] = d_in[13]; ps.p[11] = d_in[14];
    ps.p[12] = d_in[15]; ps.p[13] = d_in[16];

    // grid covers N_NODES*UNROLL_SLOTS = 240000 threads (epack pad-zero dominates)
    k_convert_init<<<(N_NODES * UNROLL_SLOTS + 255) / 256, 256, 0, stream>>>(ps, cvt, deg, cur, epack);
    k_gconv_count<<<1250 + 625, 256, 0, stream>>>(x, tc1a_w, tc1a_b, bufA, ei, ew, deg, cur, epack);

    k_gfused<false, true><<<1250, 256, 0, stream>>>(bufA, deg, cur, epack,
                                                    gc1_w, gc1_b, tc1b_w, tc1b_b,
                                                    tc2a_w, tc2a_b, nullptr, nullptr,
                                                    bufB, nullptr);
    k_gfused<true, false><<<1250, 256, 0, stream>>>(bufB, deg, cur, epack,
                                                    gc2_w, gc2_b, tc2b_w, tc2b_b,
                                                    nullptr, nullptr, fin_w, fin_b,
                                                    nullptr, (float*)d_out);
}

// Round 9
// 220.566 us; speedup vs baseline: 1.8105x; 1.8105x over previous
//
#include <hip/hip_runtime.h>
#include <hip/hip_bf16.h>
#include <stdint.h>

#define N_NODES 10000
#define N_EDGES 160000
#define BUCKET 128
#define UNROLL_SLOTS 24   // slots [0,24) processed branchlessly; k_norm zero-pads [cnt,24)

typedef unsigned short u16;
typedef unsigned int u32;
typedef short s16v8 __attribute__((ext_vector_type(8)));
typedef float f32v4 __attribute__((ext_vector_type(4)));
typedef float f32v2 __attribute__((ext_vector_type(2)));
typedef unsigned int u32v4 __attribute__((ext_vector_type(4)));
typedef unsigned int u32v2 __attribute__((ext_vector_type(2)));

__device__ __forceinline__ float bf2f(u16 v){ return __uint_as_float(((u32)v) << 16); }
__device__ __forceinline__ u16 f2bf(float f){
    u32 u = __float_as_uint(f);
    u32 r = (u + 0x7fffu + ((u >> 16) & 1u)) >> 16;
    return (u16)r;
}
// unpack u32 holding 2 bf16 -> float2 (lo, hi)
__device__ __forceinline__ f32v2 up2(u32 v){
    f32v2 r;
    r.x = __uint_as_float(v << 16);
    r.y = __uint_as_float(v & 0xffff0000u);
    return r;
}
__device__ __forceinline__ u32 pk2(float lo, float hi){
    return (u32)f2bf(lo) | ((u32)f2bf(hi) << 16);
}

// ---------------- weights fp32->bf16 (+tconv transpose to [d][o][c]) + graph init ----------------
struct SmallPtrs { const void* p[14]; };

__device__ __constant__ const int g_seg_off[15] = {
    0, 12288, 12416, 16512, 16576, 41152, 41280,
    65856, 65984, 70080, 70144, 94720, 94848, 104064, 104076
};
// 0=straight, 1=tconv CIN=32 transpose, 2=tconv CIN=64 transpose
__device__ __constant__ const int g_seg_kind[14] = {
    1, 0, 0, 0, 2, 0, 2, 0, 0, 0, 2, 0, 0, 0
};

__global__ void k_convert_init(SmallPtrs ps, u16* __restrict__ dst,
                               float* deg, int* cur){
    int i = blockIdx.x * blockDim.x + threadIdx.x;
    if (i < 104076){
        int seg = 0, base = 0;
#pragma unroll
        for (int s = 0; s < 14; s++){
            if (i >= g_seg_off[s]){ seg = s; base = g_seg_off[s]; }
        }
        int li = i - base;
        float v = ((const float*)ps.p[seg])[li];
        int kind = g_seg_kind[seg];
        int dsto = li;
        if (kind){
            int CIN = (kind == 1) ? 32 : 64;
            int o = li / (3 * CIN);
            int rem = li - o * (3 * CIN);
            int c = rem / 3, d = rem - c * 3;
            dsto = d * 128 * CIN + o * CIN + c;     // [d][o][c]
        }
        dst[base + dsto] = f2bf(v);
    }
    if (i < N_NODES){ deg[i] = 1.0f; cur[i] = 0; }
}

// ---------------- merged: gconv32 (blocks 0..1249) || deg + bucket-scatter (1250..1874) ----------------
// LDS union: xT [8][14][40] (8960 B) overlaid with Ho [8][12][72] (13824 B) -> 13.8 KB total.
__launch_bounds__(256, 4)
__global__ void k_gconv_count(const float* __restrict__ xin, const u16* __restrict__ wg,
                              const u16* __restrict__ bg, u16* __restrict__ out,
                              const int* __restrict__ ei, const float* __restrict__ ew,
                              float* deg, int* cur, int2* __restrict__ epack){
    if (blockIdx.x >= 1250){
        int e = (blockIdx.x - 1250) * 256 + threadIdx.x;
        if (e < N_EDGES){
            int s = ei[e];
            int d = ei[N_EDGES + e];
            float wv = ew[e];
            atomicAdd(&deg[d], wv);
            int p = atomicAdd(&cur[d], 1);
            if (p < BUCKET) epack[d * BUCKET + p] = make_int2(s, __float_as_int(wv));
        }
        return;
    }
    __shared__ __attribute__((aligned(16))) u16 shbuf[6912];   // 13824 B union
    u16* xT = shbuf;    // [g][row][c] = g*560 + row*40 + c  (rows 0..13, c 0..39)
    u16* Ho = shbuf;    // [g][t][o]   = g*864 + t*72 + o    (after MFMA, overwrites xT)
    int tid = threadIdx.x;
    int n0 = blockIdx.x * 8;

    int lane = tid & 63, wave = tid >> 6;
    int col = lane & 15, quad = lane >> 4;
    int o_p = wave * 16 + col, o_q = o_p + 64;

    s16v8 Bf[3][2];
#pragma unroll
    for (int pq = 0; pq < 2; pq++){
        int o = pq ? o_q : o_p;
#pragma unroll
        for (int d = 0; d < 3; d++)
            Bf[d][pq] = *(const s16v8*)(wg + d * 4096 + o * 32 + quad * 8);
    }

    for (int i = tid; i < 8 * 40; i += 256){
        int g = i / 40, c = i % 40;
        xT[g * 560 + 0 * 40 + c] = 0; xT[g * 560 + 13 * 40 + c] = 0;
    }
    {
        int g = tid >> 5, c = tid & 31;
        const float4* p = (const float4*)(xin + ((size_t)(n0 + g) * 32 + c) * 12);
        float4 v0 = p[0], v1 = p[1], v2 = p[2];
        u16* xb = xT + g * 560 + c;
        xb[1 * 40] = f2bf(v0.x);  xb[2 * 40] = f2bf(v0.y);
        xb[3 * 40] = f2bf(v0.z);  xb[4 * 40] = f2bf(v0.w);
        xb[5 * 40] = f2bf(v1.x);  xb[6 * 40] = f2bf(v1.y);
        xb[7 * 40] = f2bf(v1.z);  xb[8 * 40] = f2bf(v1.w);
        xb[9 * 40] = f2bf(v2.x);  xb[10 * 40] = f2bf(v2.y);
        xb[11 * 40] = f2bf(v2.z); xb[12 * 40] = f2bf(v2.w);
    }
    __syncthreads();

    f32v4 aP[6], aQ[6];
#pragma unroll
    for (int mt = 0; mt < 6; mt++){ aP[mt] = (f32v4)0.f; aQ[mt] = (f32v4)0.f; }
#pragma unroll
    for (int mt = 0; mt < 6; mt++){
        int m = mt * 16 + col;
        int g = m / 12, t = m - 12 * g;
#pragma unroll
        for (int d = 0; d < 3; d++){
            s16v8 a = *(const s16v8*)&xT[g * 560 + (t + d) * 40 + quad * 8];
            aP[mt] = __builtin_amdgcn_mfma_f32_16x16x32_bf16(a, Bf[d][0], aP[mt], 0, 0, 0);
            aQ[mt] = __builtin_amdgcn_mfma_f32_16x16x32_bf16(a, Bf[d][1], aQ[mt], 0, 0, 0);
        }
    }
    __syncthreads();   // all xT reads done before Ho overwrites the union buffer
    float bP = bf2f(bg[o_p]), bQ = bf2f(bg[o_q]);
#pragma unroll
    for (int mt = 0; mt < 6; mt++){
#pragma unroll
        for (int r = 0; r < 4; r++){
            int m2 = mt * 16 + quad * 4 + r;
            int g = m2 / 12, t = m2 - 12 * g;
            float pv = aP[mt][r] + bP, qv = aQ[mt][r] + bQ;
            Ho[g * 864 + t * 72 + o_p] = f2bf(pv / (1.f + __expf(-qv)));
        }
    }
    __syncthreads();
    for (int i = tid; i < 768; i += 256){
        int g = i / 96, r = i % 96, t = r / 8, ch = r % 8;
        *(s16v8*)(out + (size_t)(n0 + g) * 768 + t * 64 + ch * 8) =
            *(const s16v8*)&Ho[g * 864 + t * 72 + ch * 8];
    }
}

// ---------------- epack normalization + zero-pad slots [cnt, UNROLL_SLOTS) ----------------
// 32 threads/node, each loops 4 strided slots (vs 128 threads/node mostly idle).
__global__ void k_norm(const float* __restrict__ deg, const int* __restrict__ cur,
                       int2* __restrict__ ep){
    int i = blockIdx.x * blockDim.x + threadIdx.x;
    int n = i >> 5, slot0 = i & 31;
    if (n >= N_NODES) return;
    int cnt = cur[n]; if (cnt > BUCKET) cnt = BUCKET;
    float rdn = rsqrtf(deg[n]);
#pragma unroll
    for (int k = 0; k < 4; k++){
        int slot = slot0 + k * 32;
        if (slot < cnt){
            int2 e = ep[(size_t)n * BUCKET + slot];
            float w = __int_as_float(e.y) * rsqrtf(deg[e.x]) * rdn;
            ep[(size_t)n * BUCKET + slot].y = __float_as_int(w);
        } else if (slot < UNROLL_SLOTS){
            // pad: src=node 0 (row stays cache-hot), weight=0 -> contributes exact 0
            ep[(size_t)n * BUCKET + slot] = make_int2(0, 0);
        }
    }
}

// ---------------- merged gather + fused MFMA pipeline ----------------
// Per block: 8 nodes. Gather phase: 32 lanes/node, lane owns feats {l*8..+7, 256+l*8..+7,
// 512+l*8..+7} (3 x 512B lane-contiguous loads per edge row = 24 lines/edge, optimal).
// Serial accumulation over 24 branchless zero-padded slots -> results written straight to
// LDS bufX (no z round-trip, no shfl). Gather VMEM of some blocks overlaps MFMA of others.
// Fabric-random-traffic-bound: FETCH ~100MB/pass (= 15.4MB rows x ~7 XCDs/row) at ~2TB/s
// ~= the 59us observed; occupancy-insensitive (R4 A/B). DO NOT add code inside the
// 12-pair straight-line body or change launch_bounds: both caused spill collapses (R6/R7).
#define XIDX(g, row, c) (((g) * 14 + (row)) * 72 + (c))

#define GFMA(W, A0, A1, A2) { \
    acc[0]  += (W) * up2((A0).x); acc[1]  += (W) * up2((A0).y); \
    acc[2]  += (W) * up2((A0).z); acc[3]  += (W) * up2((A0).w); \
    acc[4]  += (W) * up2((A1).x); acc[5]  += (W) * up2((A1).y); \
    acc[6]  += (W) * up2((A1).z); acc[7]  += (W) * up2((A1).w); \
    acc[8]  += (W) * up2((A2).x); acc[9]  += (W) * up2((A2).y); \
    acc[10] += (W) * up2((A2).z); acc[11] += (W) * up2((A2).w); }

#define GPAIR(P) { \
    int4 m = *(const int4*)(eb + (P)); \
    const u16* q0 = src + (size_t)(u32)m.x * 768 + fo; \
    const u16* q1 = src + (size_t)(u32)m.z * 768 + fo; \
    u32v4 a0 = *(const u32v4*)(q0); \
    u32v4 a1 = *(const u32v4*)(q0 + 256); \
    u32v4 a2 = *(const u32v4*)(q0 + 512); \
    u32v4 c0 = *(const u32v4*)(q1); \
    u32v4 c1 = *(const u32v4*)(q1 + 256); \
    u32v4 c2 = *(const u32v4*)(q1 + 512); \
    f32v2 w0; w0.x = __int_as_float(m.y); w0.y = w0.x; \
    f32v2 w1; w1.x = __int_as_float(m.w); w1.y = w1.x; \
    GFMA(w0, a0, a1, a2); \
    GFMA(w1, c0, c1, c2); }

#define GSINGLE(P) { \
    int2 e0 = eb[(P)]; \
    const u16* q0 = src + (size_t)(u32)e0.x * 768 + fo; \
    u32v4 a0 = *(const u32v4*)(q0); \
    u32v4 a1 = *(const u32v4*)(q0 + 256); \
    u32v4 a2 = *(const u32v4*)(q0 + 512); \
    f32v2 w0; w0.x = __int_as_float(e0.y); w0.y = w0.x; \
    GFMA(w0, a0, a1, a2); }

template<bool LAST>
__launch_bounds__(256, 4)
__global__ void k_gfused(const u16* __restrict__ src,   // bufA or bufB: [n][768] bf16 rows
                         const float* __restrict__ deg, const int* __restrict__ cur,
                         const int2* __restrict__ ep,
                         const u16* __restrict__ Wmix, const u16* __restrict__ bmix,
                         const u16* __restrict__ w1, const u16* __restrict__ b1,
                         const u16* __restrict__ w2, const u16* __restrict__ b2,
                         const u16* __restrict__ fw, const u16* __restrict__ fb,
                         u16* __restrict__ outMid, float* __restrict__ outFin){
    __shared__ __attribute__((aligned(16))) u16 bufX[8 * 14 * 72];
    __shared__ __attribute__((aligned(16))) u16 bufY[8 * 14 * 72];
    int tid = threadIdx.x;
    int n0 = blockIdx.x * 8;
    int lane = tid & 63, wave = tid >> 6;
    int col = lane & 15, quad = lane >> 4;
    int o_p = wave * 16 + col, o_q = o_p + 64;

    // zero time-pad rows
    for (int i = tid; i < 8 * 72; i += 256){
        int g = i / 72, c = i % 72;
        bufX[XIDX(g, 0, c)] = 0; bufX[XIDX(g, 13, c)] = 0;
        bufY[XIDX(g, 0, c)] = 0; bufY[XIDX(g, 13, c)] = 0;
    }

    // ---- gather phase: 32 lanes per node ----
    {
        int nl = tid >> 5;               // node within block 0..7
        int l  = tid & 31;               // feature lane
        int n  = n0 + nl;
        int fo = l * 8;                  // u16 offset of this lane's first 8-feat group
        int e = cur[n]; if (e > BUCKET) e = BUCKET;   // early; used only in rare tail

        f32v2 acc[12];
        {
            float sw = 1.0f / deg[n];    // self-loop: dis[n]*1*dis[n]
            f32v2 swv; swv.x = sw; swv.y = sw;
            const u16* q = src + (size_t)n * 768 + fo;
            u32v4 s0 = *(const u32v4*)(q);
            u32v4 s1 = *(const u32v4*)(q + 256);
            u32v4 s2 = *(const u32v4*)(q + 512);
            acc[0]  = swv * up2(s0.x); acc[1]  = swv * up2(s0.y);
            acc[2]  = swv * up2(s0.z); acc[3]  = swv * up2(s0.w);
            acc[4]  = swv * up2(s1.x); acc[5]  = swv * up2(s1.y);
            acc[6]  = swv * up2(s1.z); acc[7]  = swv * up2(s1.w);
            acc[8]  = swv * up2(s2.x); acc[9]  = swv * up2(s2.y);
            acc[10] = swv * up2(s2.z); acc[11] = swv * up2(s2.w);
        }

        const int2* eb = ep + (size_t)n * BUCKET;
        // branchless: slots [0,24) zero-padded by k_norm
        GPAIR(0);  GPAIR(2);  GPAIR(4);  GPAIR(6);
        GPAIR(8);  GPAIR(10); GPAIR(12); GPAIR(14);
        GPAIR(16); GPAIR(18); GPAIR(20); GPAIR(22);

        // rare tail (P(deg>24) ~ 2%)
        if (e > UNROLL_SLOTS){
            int p = UNROLL_SLOTS;
            for (; p + 1 < e; p += 2) GPAIR(p);
            if (p < e) GSINGLE(p);
        }

        // write results straight into bufX rows 1..12 (feats gi*256 + l*8 .. +7)
#pragma unroll
        for (int gi = 0; gi < 3; gi++){
            int f0 = gi * 256 + fo;
            int t = f0 >> 6, c = f0 & 63;
            u32v4 hv;
            hv.x = pk2(acc[4 * gi + 0].x, acc[4 * gi + 0].y);
            hv.y = pk2(acc[4 * gi + 1].x, acc[4 * gi + 1].y);
            hv.z = pk2(acc[4 * gi + 2].x, acc[4 * gi + 2].y);
            hv.w = pk2(acc[4 * gi + 3].x, acc[4 * gi + 3].y);
            *(u32v4*)&bufX[XIDX(nl, 1 + t, c)] = hv;
        }
    }
    __syncthreads();

    // ---- mix MFMA: y = relu(z*W + b), 6 m-tiles ----
    {
        f32v4 accm[6];
#pragma unroll
        for (int mt = 0; mt < 6; mt++) accm[mt] = (f32v4)0.f;
#pragma unroll
        for (int ks = 0; ks < 2; ks++){
            s16v8 Bm = *(const s16v8*)(Wmix + (size_t)o_p * 64 + ks * 32 + quad * 8);
#pragma unroll
            for (int mt = 0; mt < 6; mt++){
                int m = mt * 16 + col;
                int g = m / 12, t = m - 12 * g;
                s16v8 a = *(const s16v8*)&bufX[XIDX(g, 1 + t, ks * 32 + quad * 8)];
                accm[mt] = __builtin_amdgcn_mfma_f32_16x16x32_bf16(a, Bm, accm[mt], 0, 0, 0);
            }
        }
        float bm = bf2f(bmix[o_p]);
#pragma unroll
        for (int mt = 0; mt < 6; mt++){
#pragma unroll
            for (int r = 0; r < 4; r++){
                int m2 = mt * 16 + quad * 4 + r;
                int g = m2 / 12, t = m2 - 12 * g;
                bufY[XIDX(g, 1 + t, o_p)] = f2bf(fmaxf(accm[mt][r] + bm, 0.f));
            }
        }
    }
    __syncthreads();

    // ---- gated conv 1: bufY -> bufX ----
    {
        f32v4 aP[6], aQ[6];
#pragma unroll
        for (int mt = 0; mt < 6; mt++){ aP[mt] = (f32v4)0.f; aQ[mt] = (f32v4)0.f; }
#pragma unroll
        for (int ks = 0; ks < 2; ks++){
            s16v8 Bf[3][2];
#pragma unroll
            for (int pq = 0; pq < 2; pq++){
                int o = pq ? o_q : o_p;
#pragma unroll
                for (int d = 0; d < 3; d++)
                    Bf[d][pq] = *(const s16v8*)(w1 + d * 8192 + o * 64 + ks * 32 + quad * 8);
            }
#pragma unroll
            for (int mt = 0; mt < 6; mt++){
                int m = mt * 16 + col;
                int g = m / 12, t = m - 12 * g;
#pragma unroll
                for (int d = 0; d < 3; d++){
                    s16v8 a = *(const s16v8*)&bufY[XIDX(g, t + d, ks * 32 + quad * 8)];
                    aP[mt] = __builtin_amdgcn_mfma_f32_16x16x32_bf16(a, Bf[d][0], aP[mt], 0, 0, 0);
                    aQ[mt] = __builtin_amdgcn_mfma_f32_16x16x32_bf16(a, Bf[d][1], aQ[mt], 0, 0, 0);
                }
            }
        }
        float bP = bf2f(b1[o_p]), bQ = bf2f(b1[o_q]);
#pragma unroll
        for (int mt = 0; mt < 6; mt++){
#pragma unroll
            for (int r = 0; r < 4; r++){
                int m2 = mt * 16 + quad * 4 + r;
                int g = m2 / 12, t = m2 - 12 * g;
                float pv = aP[mt][r] + bP, qv = aQ[mt][r] + bQ;
                u16 hv = f2bf(pv / (1.f + __expf(-qv)));
                if (LAST) bufX[g * 1008 + o_p * 12 + t] = hv;   // H2[g][c*12+t]
                else      bufX[XIDX(g, 1 + t, o_p)] = hv;
            }
        }
    }
    __syncthreads();

    if (!LAST){
        // ---- gated conv 2: bufX -> bufY -> outMid ----
        f32v4 aP[6], aQ[6];
#pragma unroll
        for (int mt = 0; mt < 6; mt++){ aP[mt] = (f32v4)0.f; aQ[mt] = (f32v4)0.f; }
#pragma unroll
        for (int ks = 0; ks < 2; ks++){
            s16v8 Bf[3][2];
#pragma unroll
            for (int pq = 0; pq < 2; pq++){
                int o = pq ? o_q : o_p;
#pragma unroll
                for (int d = 0; d < 3; d++)
                    Bf[d][pq] = *(const s16v8*)(w2 + d * 8192 + o * 64 + ks * 32 + quad * 8);
            }
#pragma unroll
            for (int mt = 0; mt < 6; mt++){
                int m = mt * 16 + col;
                int g = m / 12, t = m - 12 * g;
#pragma unroll
                for (int d = 0; d < 3; d++){
                    s16v8 a = *(const s16v8*)&bufX[XIDX(g, t + d, ks * 32 + quad * 8)];
                    aP[mt] = __builtin_amdgcn_mfma_f32_16x16x32_bf16(a, Bf[d][0], aP[mt], 0, 0, 0);
                    aQ[mt] = __builtin_amdgcn_mfma_f32_16x16x32_bf16(a, Bf[d][1], aQ[mt], 0, 0, 0);
                }
            }
        }
        float bP = bf2f(b2[o_p]), bQ = bf2f(b2[o_q]);
#pragma unroll
        for (int mt = 0; mt < 6; mt++){
#pragma unroll
            for (int r = 0; r < 4; r++){
                int m2 = mt * 16 + quad * 4 + r;
                int g = m2 / 12, t = m2 - 12 * g;
                float pv = aP[mt][r] + bP, qv = aQ[mt][r] + bQ;
                bufY[XIDX(g, 1 + t, o_p)] = f2bf(pv / (1.f + __expf(-qv)));
            }
        }
        __syncthreads();
        for (int i = tid; i < 768; i += 256){
            int g = i / 96, r = i % 96, t = r / 8, ch = r % 8;
            *(s16v8*)(outMid + (size_t)(n0 + g) * 768 + t * 64 + ch * 8) =
                *(const s16v8*)&bufY[XIDX(g, 1 + t, ch * 8)];
        }
    } else {
        // ---- final: out[g][o] = sum_k H2[g][k]*fw[o][k] + fb[o] (wave 0; 8 nodes in rows 0..7) ----
        if (wave == 0){
            f32v4 accF = {0.f, 0.f, 0.f, 0.f};
            int g8 = col & 7;
#pragma unroll
            for (int ks = 0; ks < 24; ks++){
                s16v8 a = *(const s16v8*)&bufX[g8 * 1008 + ks * 32 + quad * 8];
                s16v8 bfr = {0, 0, 0, 0, 0, 0, 0, 0};
                if (col < 12)
                    bfr = *(const s16v8*)(fw + (size_t)col * 768 + ks * 32 + quad * 8);
                accF = __builtin_amdgcn_mfma_f32_16x16x32_bf16(a, bfr, accF, 0, 0, 0);
            }
            if (col < 12 && quad < 2){
                float bb = bf2f(fb[col]);
#pragma unroll
                for (int r = 0; r < 4; r++){
                    int g = quad * 4 + r;
                    outFin[(size_t)(n0 + g) * 12 + col] = accF[r] + bb;
                }
            }
        }
    }
}

// ---------------- launch ----------------
static inline size_t align256(size_t x){ return (x + 255) & ~(size_t)255; }

extern "C" void kernel_launch(void* const* d_in, const int* in_sizes, int n_in,
                              void* d_out, int out_size, void* d_ws, size_t ws_size,
                              hipStream_t stream){
    const float* x  = (const float*)d_in[0];
    const int* ei   = (const int*)d_in[1];
    const float* ew = (const float*)d_in[2];

    char* w = (char*)d_ws;
    u16* bufA    = (u16*)w;  w += align256((size_t)N_NODES * 768 * sizeof(u16));
    u16* bufB    = (u16*)w;  w += align256((size_t)N_NODES * 768 * sizeof(u16));
    float* deg   = (float*)w; w += align256(N_NODES * sizeof(float));
    int* cur     = (int*)w;   w += align256(N_NODES * sizeof(int));
    int2* epack  = (int2*)w;  w += align256((size_t)N_NODES * BUCKET * sizeof(int2));
    u16* cvt     = (u16*)w;   w += align256(104076 * sizeof(u16));

    u16* tc1a_w = cvt + 0;        // [d][128][32]
    u16* tc1a_b = cvt + 12288;
    u16* gc1_w  = cvt + 12416;
    u16* gc1_b  = cvt + 16512;
    u16* tc1b_w = cvt + 16576;    // [d][128][64]
    u16* tc1b_b = cvt + 41152;
    u16* tc2a_w = cvt + 41280;    // [d][128][64]
    u16* tc2a_b = cvt + 65856;
    u16* gc2_w  = cvt + 65984;
    u16* gc2_b  = cvt + 70080;
    u16* tc2b_w = cvt + 70144;    // [d][128][64]
    u16* tc2b_b = cvt + 94720;
    u16* fin_w  = cvt + 94848;
    u16* fin_b  = cvt + 104064;

    SmallPtrs ps;
    ps.p[0]  = d_in[3];  ps.p[1]  = d_in[4];
    ps.p[2]  = d_in[5];  ps.p[3]  = d_in[6];
    ps.p[4]  = d_in[7];  ps.p[5]  = d_in[8];
    ps.p[6]  = d_in[9];  ps.p[7]  = d_in[10];
    ps.p[8]  = d_in[11]; ps.p[9]  = d_in[12];
    ps.p[10] = d_in[13]; ps.p[11] = d_in[14];
    ps.p[12] = d_in[15]; ps.p[13] = d_in[16];

    k_convert_init<<<(104076 + 255) / 256, 256, 0, stream>>>(ps, cvt, deg, cur);
    k_gconv_count<<<1250 + 625, 256, 0, stream>>>(x, tc1a_w, tc1a_b, bufA, ei, ew, deg, cur, epack);
    k_norm<<<(N_NODES * 32 + 255) / 256, 256, 0, stream>>>(deg, cur, epack);

    k_gfused<false><<<1250, 256, 0, stream>>>(bufA, deg, cur, epack,
                                              gc1_w, gc1_b, tc1b_w, tc1b_b,
                                              tc2a_w, tc2a_b, nullptr, nullptr,
                                              bufB, nullptr);
    k_gfused<true><<<1250, 256, 0, stream>>>(bufB, deg, cur, epack,
                                             gc2_w, gc2_b, tc2b_w, tc2b_b,
                                             nullptr, nullptr, fin_w, fin_b,
                                             nullptr, (float*)d_out);
}